// Round 22
// baseline (145.645 us; speedup 1.0000x reference)
//
#include <hip/hip_runtime.h>

#define LSEQ 512
#define NB 64
#define NCHUNK 51  // 16*51 = 816 >= 512 + 3*80 + 63 = 815 steps

// lanes 1..63 <- x[lane-1]; lane 0 <- old[0] (wave_shr:1, bound_ctrl=0).
// Injection MUST be fused into the old operand (lane-varying ternary around
// the DPP lets the compiler run v_mov_b32_dpp with exec={1..63}; exec-off
// SOURCE lanes are invalid -> lane 1 reads 0. R12/R19/R20 all failed on this).
__device__ __forceinline__ float dpp_shr1_inj(float inj, float x) {
  return __int_as_float(__builtin_amdgcn_update_dpp(
      __float_as_int(inj), __float_as_int(x), 0x138, 0xF, 0xF, false));
}

__device__ __forceinline__ float rdlane(float x, int u) {
  return __int_as_float(__builtin_amdgcn_readlane(__float_as_int(x), u));
}

// (d,e) pair encodes v = d - log2(e); exact softmin, log deferred to the end.
__device__ __forceinline__ void renorm(float& d, float& e) {
  const int eb = __float_as_int(e);
  const int E = (eb >> 23) - 127;
  e = __int_as_float((eb & 0x007FFFFF) | 0x3F800000);
  d -= (float)E;
}

// One 16-step chunk, 2 rows/lane (identical arithmetic/schedule to R21).
template <bool FULL>
__device__ __forceinline__ void chunk16(
    int cbase, const float* tgpad, const float2* ring2P, float2* ring2W,
    float p0, float p1, bool is_wr, int lane, float& v0d, float& v0e,
    float& v1d, float& v1e, float& r0d, float& r0e) {
  renorm(v0d, v0e);
  renorm(v1d, v1e);

  // per-lane target registers for this chunk: tt[u] = tg'[cbase+u-lane]
  float tt[16];
  const int tb = 64 + cbase - lane;  // front pad 64 keeps index >= 1
#pragma unroll
  for (int k = 0; k < 16; ++k) tt[k] = tgpad[tb + k];

  // ring injection -> SGPRs: lane k (k<16) holds slot cbase+1+k
  const float2 rj = ring2P[(cbase + 1 + (lane & 15)) & 127];
  float sjd[16], sje[16];
#pragma unroll
  for (int k = 0; k < 16; ++k) {
    sjd[k] = rdlane(rj.x, k);
    sje[k] = rdlane(rj.y, k);
  }

  float vvd[16], vve[16];
#pragma unroll
  for (int u = 0; u < 16; ++u) {
    // R'[i0-1][j] pair: lanes 1..63 from lane-1's v1; lane 0 from ring SGPR
    const float r1d = dpp_shr1_inj(sjd[u], v1d);
    const float r1e = dpp_shr1_inj(sje[u], v1e);
    const float tcu = tt[u];  // target'[j-1], register-resident
    // cell0 (row i0): diag (r0d,r0e), up (r1d,r1e), left (v0d,v0e)
    const float diff0 = p0 - tcu;
    const float M0 = fminf(fminf(r0d, r1d), v0d);
    const float d0 = __builtin_fmaf(diff0, diff0, M0);
    // cell1 (row i1): diag (v0d,v0e)_old, up (d0,e0), left (v1d,v1e)
    const float diff1 = p1 - tcu;
    const float M1 = fminf(fminf(v0d, d0), v1d);
    const float d1 = __builtin_fmaf(diff1, diff1, M1);
    const float x0 = __builtin_amdgcn_exp2f(M0 - r0d);
    const float x1 = __builtin_amdgcn_exp2f(M0 - r1d);
    const float x2 = __builtin_amdgcn_exp2f(M0 - v0d);
    const float x3 = __builtin_amdgcn_exp2f(M1 - v0d);
    const float x4 = __builtin_amdgcn_exp2f(M1 - d0);
    const float x5 = __builtin_amdgcn_exp2f(M1 - v1d);
    const float e0 = __builtin_fmaf(x2, v0e, __builtin_fmaf(x1, r1e, x0 * r0e));
    const float e1 = __builtin_fmaf(x5, v1e, __builtin_fmaf(x4, e0, x3 * v0e));
    vvd[u] = d1;
    vve[u] = e1;
    if (FULL) {
      v0d = d0; v0e = e0; v1d = d1; v1e = e1;
    } else {
      const int j = cbase + 1 + u - lane;
      const bool act = ((unsigned)(j - 1)) < (unsigned)LSEQ;
      v0d = act ? d0 : v0d; v0e = act ? e0 : v0e;  // inactive lanes keep
      v1d = act ? d1 : v1d; v1e = act ? e1 : v1e;  // (INF,1); NaN discarded
    }
    r0d = r1d;
    r0e = r1e;
  }

  if (is_wr) {  // lane 63 publishes row 128(w+1) = its i1
    const int j0 = cbase - 62;
#pragma unroll
    for (int k = 0; k < 16; ++k) {
      if (FULL || (((unsigned)(j0 + k - 1)) < (unsigned)LSEQ))
        ring2W[(j0 + k) & 127] = make_float2(vvd[k], vve[k]);
    }
  }
}

// Soft-DTW banded wavefront, TWO BATCHES PER BLOCK (8 waves): waves 0-3 =
// batch A, waves 4-7 = batch B. Wave i lands on SIMD i&3 -> each SIMD runs
// one A-wave + one B-wave: two independent instruction streams whose TLP
// fills dependent-latency stalls (R11 vs R13: 2 waves/SIMD = 68% issue
// efficiency vs 43% at 1 wave/SIMD; intra-wave reordering was proven useless
// in R14/15/17/18). Per batch: identical R21/R13 schedule — lane l of wave w
// owns rows 128w+2l+1,+2; j = s-80w-l; ring write/read separated by the
// top-of-chunk barrier (barrier spans both batches; schedules identical).
__global__ __launch_bounds__(512) void dtw_band(
    const float* __restrict__ pred, const float* __restrict__ target,
    float* __restrict__ part) {
  const int b2 = blockIdx.x;     // handles batches 2*b2, 2*b2+1
  const int tid = threadIdx.x;   // 0..511
  const int half = tid >> 8;     // 0 = batch A, 1 = batch B
  const int ltid = tid & 255;    // local tid within the batch
  const int w = ltid >> 6;       // local wave 0..3
  const int lane = tid & 63;
  const int batch = 2 * b2 + half;
  const bool is_wr = (lane == 63) && (w < 3);

  __shared__ float tgpad[2][640];       // [64 pad][512 data][64 pad] per batch
  __shared__ float2 rings2[2][4][128];  // rows 0..2: interfaces; row 3: INF

  const float SC = 3.79828146f;  // sqrt(C1), C1 = (1/g)*log2(e), g = 0.1
  const float2 pp = ((const float2*)(pred + batch * LSEQ))[ltid];
  const float p0 = pp.x * SC, p1 = pp.y * SC;  // rows 2*ltid+1, 2*ltid+2
  const float2 tt = ((const float2*)(target + batch * LSEQ))[ltid];
  ((float2*)(tgpad[half] + 64))[ltid] = make_float2(tt.x * SC, tt.y * SC);
  if (ltid < 64) {
    tgpad[half][ltid] = 0.0f;        // pads: read only by inactive cells
    tgpad[half][576 + ltid] = 0.0f;
  }
  ((float2*)rings2[half])[ltid] = make_float2(INFINITY, 1.0f);
  ((float2*)rings2[half])[ltid + 256] = make_float2(INFINITY, 1.0f);

  const int lag = w * 80;
  const int cw0 = 5 * w;  // wave-active chunks: [cw0, cw0+35]
  const float2* __restrict__ ring2P = rings2[half][w == 0 ? 3 : w - 1];
  float2* __restrict__ ring2W = rings2[half][w];
  const float* __restrict__ tgp = tgpad[half];

  float v0d = INFINITY, v0e = 1.0f;           // R'[i0][j-1]
  float v1d = INFINITY, v1e = 1.0f;           // R'[i1][j-1]
  float r0d = (ltid == 0) ? 0.0f : INFINITY;  // R'[i0-1][j-1]; seed R'[0][0]
  float r0e = 1.0f;

  for (int c = 0; c < NCHUNK; ++c) {
    __syncthreads();  // top of chunk c (also orders init writes at c=0)
    if (c < cw0 || c > cw0 + 35) continue;  // wave-uniform
    const int cbase = 16 * c - lag;
    if (c >= cw0 + 4 && c <= cw0 + 31)
      chunk16<true>(cbase, tgp, ring2P, ring2W, p0, p1, is_wr, lane, v0d, v0e,
                    v1d, v1e, r0d, r0e);
    else
      chunk16<false>(cbase, tgp, ring2P, ring2W, p0, p1, is_wr, lane, v0d,
                     v0e, v1d, v1e, r0d, r0e);
  }

  if (ltid == 255)  // row 512 = local wave 3 lane 63 i1; unscale by 1/C1
    part[batch] = (v1d - __builtin_amdgcn_logf(v1e)) * 0.069314718f;
}

__global__ void dtw_reduce(const float* __restrict__ part,
                           float* __restrict__ out) {
  float v = part[threadIdx.x];
#pragma unroll
  for (int o = 32; o > 0; o >>= 1) v += __shfl_down(v, o);
  if (threadIdx.x == 0) out[0] = v * (1.0f / NB);
}

extern "C" void kernel_launch(void* const* d_in, const int* in_sizes, int n_in,
                              void* d_out, int out_size, void* d_ws,
                              size_t ws_size, hipStream_t stream) {
  const float* pred = (const float*)d_in[0];
  const float* target = (const float*)d_in[1];
  float* part = (float*)d_ws;

  dtw_band<<<NB / 2, 512, 0, stream>>>(pred, target, part);
  dtw_reduce<<<1, 64, 0, stream>>>(part, (float*)d_out);
}

// Round 23
// 97.137 us; speedup vs baseline: 1.4994x; 1.4994x over previous
//
#include <hip/hip_runtime.h>

#define LSEQ 512
#define NB 64
#define NCHUNK 51  // 16*51 = 816 >= 512 + 3*80 + 63 = 815 steps

// lanes 1..63 <- x[lane-1]; lane 0 <- old[0] (wave_shr:1, bound_ctrl=0).
// Injection MUST be fused into the old operand (a lane-varying ternary around
// the DPP lets the compiler run v_mov_b32_dpp with exec={1..63}; exec-off
// SOURCE lanes are invalid -> lane 1 reads 0. R12/R19/R20 all failed on this).
__device__ __forceinline__ float dpp_shr1_inj(float inj, float x) {
  return __int_as_float(__builtin_amdgcn_update_dpp(
      __float_as_int(inj), __float_as_int(x), 0x138, 0xF, 0xF, false));
}

__device__ __forceinline__ float rdlane(float x, int u) {
  return __int_as_float(__builtin_amdgcn_readlane(__float_as_int(x), u));
}

// Schraudolph exp2 for x <= 0: 3 full-rate VALU ops, no trans pipe.
// as_float((int)(2^23*x + 127*2^23)) = 2^floor(x) * (1 + frac(x)) — exact at
// x = 0 (the argmin term's weight is exactly 1.0, killing the dominant bias;
// only near-tie secondary terms carry the <= +6% interp error). Clamp at
// -126: keeps the int in range, maps -INF and (via fmax's NaN rule) NaN to a
// ~1e-38 term. R22 showed stalls are pipe-structural (2nd wave absorbed
// nothing); the 6 quarter-rate v_exp_f32 per step are the suspect pipe.
__device__ __forceinline__ float exp2_fast(float x) {
  const float xc = fmaxf(x, -126.0f);
  const float f = __builtin_fmaf(xc, 8388608.0f, 1065353216.0f);
  return __int_as_float((int)f);
}

// (d,e) pair encodes v = d - log2(e); exact softmin, log deferred to the end.
__device__ __forceinline__ void renorm(float& d, float& e) {
  const int eb = __float_as_int(e);
  const int E = (eb >> 23) - 127;
  e = __int_as_float((eb & 0x007FFFFF) | 0x3F800000);
  d -= (float)E;
}

// One 16-step chunk, 2 rows/lane (R21 schedule; exp2 -> bit-hack).
template <bool FULL>
__device__ __forceinline__ void chunk16(
    int cbase, const float* tgpad, const float2* ring2P, float2* ring2W,
    float p0, float p1, bool is_wr, int lane, float& v0d, float& v0e,
    float& v1d, float& v1e, float& r0d, float& r0e) {
  renorm(v0d, v0e);
  renorm(v1d, v1e);

  // per-lane target registers for this chunk: tt[u] = tg'[cbase+u-lane]
  float tt[16];
  const int tb = 64 + cbase - lane;  // front pad 64 keeps index >= 1
#pragma unroll
  for (int k = 0; k < 16; ++k) tt[k] = tgpad[tb + k];

  // ring injection -> SGPRs: lane k (k<16) holds slot cbase+1+k
  const float2 rj = ring2P[(cbase + 1 + (lane & 15)) & 127];
  float sjd[16], sje[16];
#pragma unroll
  for (int k = 0; k < 16; ++k) {
    sjd[k] = rdlane(rj.x, k);
    sje[k] = rdlane(rj.y, k);
  }

  float vvd[16], vve[16];
#pragma unroll
  for (int u = 0; u < 16; ++u) {
    // R'[i0-1][j] pair: lanes 1..63 from lane-1's v1; lane 0 from ring SGPR
    const float r1d = dpp_shr1_inj(sjd[u], v1d);
    const float r1e = dpp_shr1_inj(sje[u], v1e);
    const float tcu = tt[u];  // target'[j-1], register-resident
    // cell0 (row i0): diag (r0d,r0e), up (r1d,r1e), left (v0d,v0e)
    const float diff0 = p0 - tcu;
    const float M0 = fminf(fminf(r0d, r1d), v0d);
    const float d0 = __builtin_fmaf(diff0, diff0, M0);
    // cell1 (row i1): diag (v0d,v0e)_old, up (d0,e0), left (v1d,v1e)
    const float diff1 = p1 - tcu;
    const float M1 = fminf(fminf(v0d, d0), v1d);
    const float d1 = __builtin_fmaf(diff1, diff1, M1);
    const float x0 = exp2_fast(M0 - r0d);
    const float x1 = exp2_fast(M0 - r1d);
    const float x2 = exp2_fast(M0 - v0d);
    const float x3 = exp2_fast(M1 - v0d);
    const float x4 = exp2_fast(M1 - d0);
    const float x5 = exp2_fast(M1 - v1d);
    const float e0 = __builtin_fmaf(x2, v0e, __builtin_fmaf(x1, r1e, x0 * r0e));
    const float e1 = __builtin_fmaf(x5, v1e, __builtin_fmaf(x4, e0, x3 * v0e));
    vvd[u] = d1;
    vve[u] = e1;
    if (FULL) {
      v0d = d0; v0e = e0; v1d = d1; v1e = e1;
    } else {
      const int j = cbase + 1 + u - lane;
      const bool act = ((unsigned)(j - 1)) < (unsigned)LSEQ;
      v0d = act ? d0 : v0d; v0e = act ? e0 : v0e;  // inactive lanes keep
      v1d = act ? d1 : v1d; v1e = act ? e1 : v1e;  // (INF,1); garbage discarded
    }
    r0d = r1d;
    r0e = r1e;
  }

  if (is_wr) {  // lane 63 publishes row 128(w+1) = its i1
    const int j0 = cbase - 62;
#pragma unroll
    for (int k = 0; k < 16; ++k) {
      if (FULL || (((unsigned)(j0 + k - 1)) < (unsigned)LSEQ))
        ring2W[(j0 + k) & 127] = make_float2(vvd[k], vve[k]);
    }
  }
}

// Soft-DTW banded wavefront, one block per batch, 4 waves x 64 lanes x 2 rows.
// Lane l of wave w owns rows 128w+2l+1, +2; column j = s - 80w - l at step s.
// Ring (lag=80): entry col J read by wave w at top of chunk c was written by
// wave w-1 in its chunk c-1, burst before the top-of-c barrier; concurrent
// writes land +18..+33 past the read window (disjoint mod 128).
__global__ __launch_bounds__(256) void dtw_band(
    const float* __restrict__ pred, const float* __restrict__ target,
    float* __restrict__ part) {
  const int b = blockIdx.x;
  const int tid = threadIdx.x;  // 0..255
  const int w = tid >> 6;
  const int lane = tid & 63;
  const bool is_wr = (lane == 63) && (w < 3);

  __shared__ float tgpad[640];       // [64 pad][512 data][64 pad]
  __shared__ float2 rings2[4][128];  // rows 0..2: interfaces; row 3: INF dummy

  const float SC = 3.79828146f;  // sqrt(C1), C1 = (1/g)*log2(e), g = 0.1
  const float2 pp = ((const float2*)(pred + b * LSEQ))[tid];
  const float p0 = pp.x * SC, p1 = pp.y * SC;  // rows 2*tid+1, 2*tid+2
  const float2 tt = ((const float2*)(target + b * LSEQ))[tid];
  ((float2*)(tgpad + 64))[tid] = make_float2(tt.x * SC, tt.y * SC);
  if (tid < 64) {
    tgpad[tid] = 0.0f;        // pads: read only by inactive cells
    tgpad[576 + tid] = 0.0f;
  }
  ((float2*)rings2)[tid] = make_float2(INFINITY, 1.0f);
  ((float2*)rings2)[tid + 256] = make_float2(INFINITY, 1.0f);

  const int lag = w * 80;
  const int cw0 = 5 * w;  // wave-active chunks: [cw0, cw0+35]
  const float2* __restrict__ ring2P = rings2[w == 0 ? 3 : w - 1];
  float2* __restrict__ ring2W = rings2[w];

  float v0d = INFINITY, v0e = 1.0f;          // R'[i0][j-1]
  float v1d = INFINITY, v1e = 1.0f;          // R'[i1][j-1]
  float r0d = (tid == 0) ? 0.0f : INFINITY;  // R'[i0-1][j-1]; seed R'[0][0]
  float r0e = 1.0f;

  for (int c = 0; c < NCHUNK; ++c) {
    __syncthreads();  // top of chunk c (also orders init writes at c=0)
    if (c < cw0 || c > cw0 + 35) continue;  // wave-uniform
    const int cbase = 16 * c - lag;
    if (c >= cw0 + 4 && c <= cw0 + 31)
      chunk16<true>(cbase, tgpad, ring2P, ring2W, p0, p1, is_wr, lane, v0d,
                    v0e, v1d, v1e, r0d, r0e);
    else
      chunk16<false>(cbase, tgpad, ring2P, ring2W, p0, p1, is_wr, lane, v0d,
                     v0e, v1d, v1e, r0d, r0e);
  }

  if (tid == 255)  // row 512 = wave 3 lane 63 i1; unscale by 1/C1 = g*ln2
    part[b] = (v1d - __builtin_amdgcn_logf(v1e)) * 0.069314718f;
}

__global__ void dtw_reduce(const float* __restrict__ part,
                           float* __restrict__ out) {
  float v = part[threadIdx.x];
#pragma unroll
  for (int o = 32; o > 0; o >>= 1) v += __shfl_down(v, o);
  if (threadIdx.x == 0) out[0] = v * (1.0f / NB);
}

extern "C" void kernel_launch(void* const* d_in, const int* in_sizes, int n_in,
                              void* d_out, int out_size, void* d_ws,
                              size_t ws_size, hipStream_t stream) {
  const float* pred = (const float*)d_in[0];
  const float* target = (const float*)d_in[1];
  float* part = (float*)d_ws;

  dtw_band<<<NB, 256, 0, stream>>>(pred, target, part);
  dtw_reduce<<<1, 64, 0, stream>>>(part, (float*)d_out);
}

// Round 24
// 85.084 us; speedup vs baseline: 1.7118x; 1.1417x over previous
//
#include <hip/hip_runtime.h>

#define LSEQ 512
#define NB 64
#define NCHUNK 51  // 16*51 = 816 >= 512 + 3*80 + 63 = 815 steps

// lanes 1..63 <- x[lane-1]; lane 0 <- old[0] (wave_shr:1, bound_ctrl=0).
// Injection MUST be fused into the old operand (lane-varying ternary around
// the DPP lets the compiler run it with exec={1..63}; exec-off SOURCE lanes
// are invalid -> lane 1 reads garbage. R12/R19/R20 all failed on this).
__device__ __forceinline__ float dpp_shr1_inj(float inj, float x) {
  return __int_as_float(__builtin_amdgcn_update_dpp(
      __float_as_int(inj), __float_as_int(x), 0x138, 0xF, 0xF, false));
}

__device__ __forceinline__ float rdlane(float x, int u) {
  return __int_as_float(__builtin_amdgcn_readlane(__float_as_int(x), u));
}

// Schraudolph exp2 for x <= 0: fmax + fma + cvt, full-rate VALU, no trans.
// Exact at x=0 (argmin weight = 1.0). -INF / NaN (from INF-INF) -> 2^-126.
// R23 measured absmax 0.0 with this in the pair form.
__device__ __forceinline__ float exp2_fast(float x) {
  const float xc = fmaxf(x, -126.0f);
  const float f = __builtin_fmaf(xc, 8388608.0f, 1065353216.0f);
  return __int_as_float((int)f);
}
// Inverse-Schraudolph log2 for e in [1,4): (as_int(e)-1.0f_bits) * 2^-23.
// Max error 0.086 (bits) -> 0.006 unscaled per cell; exact at e=1 and e=2.
__device__ __forceinline__ float log2_fast(float e) {
  return (float)(__float_as_int(e) - 1065353216) * 1.1920929e-7f;
}

// One 16-step chunk, 2 rows/lane, DIRECT-form softmin (no (d,e) pair):
// v = d + M - log2(1 + exp2(M-med) + exp2(M-max)), all full-rate VALU.
// The pair form existed to keep log off the serial chain; with log2_fast
// (3 VALU ops) that's moot. Halves cross-lane ops (1 dpp/step), ring
// traffic, and readlanes; removes renorm and 6 e-fmas per step.
template <bool FULL>
__device__ __forceinline__ void chunk16(
    int cbase, const float* tgpad, const float* ringP, float* ringW, float p0,
    float p1, bool is_wr, int lane, float& v0, float& v1, float& r0) {
  // per-lane target registers for this chunk: tt[u] = tg'[cbase+u-lane]
  float tt[16];
  const int tb = 64 + cbase - lane;  // front pad 64 keeps index >= 1
#pragma unroll
  for (int k = 0; k < 16; ++k) tt[k] = tgpad[tb + k];

  // ring injection -> SGPRs: lane k (k<16) holds slot cbase+1+k
  const float rj = ringP[(cbase + 1 + (lane & 15)) & 127];
  float sj[16];
#pragma unroll
  for (int k = 0; k < 16; ++k) sj[k] = rdlane(rj, k);

  float vv[16];
#pragma unroll
  for (int u = 0; u < 16; ++u) {
    // R'[i0-1][j]: lanes 1..63 from lane-1's v1; lane 0 from ring SGPR
    const float r1 = dpp_shr1_inj(sj[u], v1);
    const float tcu = tt[u];
    // cell0 (row i0): diag r0, up r1, left v0
    const float diff0 = p0 - tcu;
    const float M0 = fminf(fminf(r0, r1), v0);
    const float md0 = __builtin_amdgcn_fmed3f(r0, r1, v0);
    const float mx0 = fmaxf(fmaxf(r0, r1), v0);
    const float e0 =
        1.0f + (exp2_fast(M0 - md0) + exp2_fast(M0 - mx0));  // in [1,3]
    const float d0 =
        __builtin_fmaf(diff0, diff0, M0) - log2_fast(e0);
    // cell1 (row i1): diag v0_old, up d0, left v1
    const float diff1 = p1 - tcu;
    const float M1 = fminf(fminf(v0, d0), v1);
    const float md1 = __builtin_amdgcn_fmed3f(v0, d0, v1);
    const float mx1 = fmaxf(fmaxf(v0, d0), v1);
    const float e1 =
        1.0f + (exp2_fast(M1 - md1) + exp2_fast(M1 - mx1));
    const float d1 =
        __builtin_fmaf(diff1, diff1, M1) - log2_fast(e1);
    vv[u] = d1;
    if (FULL) {
      v0 = d0;
      v1 = d1;
    } else {
      const int j = cbase + 1 + u - lane;
      const bool act = ((unsigned)(j - 1)) < (unsigned)LSEQ;
      v0 = act ? d0 : v0;  // inactive lanes keep INF (INF propagates cleanly:
      v1 = act ? d1 : v1;  // NaN args -> exp2_fast 2^-126, v = INF - eps)
    }
    r0 = r1;
  }

  if (is_wr) {  // lane 63 publishes row 128(w+1) = its i1 (8x ds_write_b64)
    const int j0 = cbase - 62;  // even -> float2 pairs never straddle wrap
#pragma unroll
    for (int k = 0; k < 8; ++k) {
      if (FULL || (((unsigned)(j0 + 2 * k - 1)) < (unsigned)LSEQ))
        *(float2*)&ringW[(j0 + 2 * k) & 127] =
            make_float2(vv[2 * k], vv[2 * k + 1]);
      else if (((unsigned)(j0 + 2 * k)) < (unsigned)LSEQ)  // only 2nd valid
        ringW[(j0 + 2 * k + 1) & 127] = vv[2 * k + 1];
    }
  }
}

// Soft-DTW banded wavefront, one block per batch, 4 waves x 64 lanes x 2 rows.
// Lane l of wave w owns rows 128w+2l+1, +2; column j = s - 80w - l at step s.
// Ring (lag=80): entry col J read by wave w at top of chunk c was written by
// wave w-1 in its chunk c-1, burst before the top-of-c barrier; concurrent
// writes land +18..+33 past the read window (disjoint mod 128).
__global__ __launch_bounds__(256) void dtw_band(
    const float* __restrict__ pred, const float* __restrict__ target,
    float* __restrict__ part) {
  const int b = blockIdx.x;
  const int tid = threadIdx.x;  // 0..255
  const int w = tid >> 6;
  const int lane = tid & 63;
  const bool is_wr = (lane == 63) && (w < 3);

  __shared__ float tgpad[640];     // [64 pad][512 data][64 pad]
  __shared__ float rings[4][128];  // rows 0..2: interfaces; row 3: INF dummy

  const float SC = 3.79828146f;  // sqrt(C1), C1 = (1/g)*log2(e), g = 0.1
  const float2 pp = ((const float2*)(pred + b * LSEQ))[tid];
  const float p0 = pp.x * SC, p1 = pp.y * SC;  // rows 2*tid+1, 2*tid+2
  const float2 tt = ((const float2*)(target + b * LSEQ))[tid];
  ((float2*)(tgpad + 64))[tid] = make_float2(tt.x * SC, tt.y * SC);
  if (tid < 64) {
    tgpad[tid] = 0.0f;        // pads: read only by inactive cells
    tgpad[576 + tid] = 0.0f;
  }
  ((float2*)rings)[tid] = make_float2(INFINITY, INFINITY);

  const int lag = w * 80;
  const int cw0 = 5 * w;  // wave-active chunks: [cw0, cw0+35]
  const float* __restrict__ ringP = rings[w == 0 ? 3 : w - 1];
  float* __restrict__ ringW = rings[w];

  float v0 = INFINITY;                      // R'[i0][j-1]
  float v1 = INFINITY;                      // R'[i1][j-1]
  float r0 = (tid == 0) ? 0.0f : INFINITY;  // R'[i0-1][j-1]; seed R'[0][0]

  for (int c = 0; c < NCHUNK; ++c) {
    __syncthreads();  // top of chunk c (also orders init writes at c=0)
    if (c < cw0 || c > cw0 + 35) continue;  // wave-uniform
    const int cbase = 16 * c - lag;
    if (c >= cw0 + 4 && c <= cw0 + 31)
      chunk16<true>(cbase, tgpad, ringP, ringW, p0, p1, is_wr, lane, v0, v1,
                    r0);
    else
      chunk16<false>(cbase, tgpad, ringP, ringW, p0, p1, is_wr, lane, v0, v1,
                     r0);
  }

  if (tid == 255)  // row 512 = wave 3 lane 63 i1; unscale by 1/C1 = g*ln2
    part[b] = v1 * 0.069314718f;
}

__global__ void dtw_reduce(const float* __restrict__ part,
                           float* __restrict__ out) {
  float v = part[threadIdx.x];
#pragma unroll
  for (int o = 32; o > 0; o >>= 1) v += __shfl_down(v, o);
  if (threadIdx.x == 0) out[0] = v * (1.0f / NB);
}

extern "C" void kernel_launch(void* const* d_in, const int* in_sizes, int n_in,
                              void* d_out, int out_size, void* d_ws,
                              size_t ws_size, hipStream_t stream) {
  const float* pred = (const float*)d_in[0];
  const float* target = (const float*)d_in[1];
  float* part = (float*)d_ws;

  dtw_band<<<NB, 256, 0, stream>>>(pred, target, part);
  dtw_reduce<<<1, 64, 0, stream>>>(part, (float*)d_out);
}